// Round 6
// baseline (147.710 us; speedup 1.0000x reference)
//
#include <hip/hip_runtime.h>
#include <hip/hip_bf16.h>

// Problem sizes (fixed by the reference)
#define LROWS 8192
#define BROWS 4096
#define DDIM  1024

typedef __attribute__((ext_vector_type(4)))  int   i32x4;
typedef __attribute__((ext_vector_type(8)))  int   i32x8;
typedef __attribute__((ext_vector_type(16))) float f32x16;

// address-space-qualified pointer typedefs for global_load_lds
typedef const unsigned int __attribute__((address_space(1))) gu32;
typedef unsigned int       __attribute__((address_space(3))) su32;

// pack 4 floats -> 4 fp8 e4m3 bytes (OCP e4m3fn on gfx950)
__device__ inline unsigned int pack_fp8x4(float4 v) {
    unsigned int w = 0;
    w = __builtin_amdgcn_cvt_pk_fp8_f32(v.x, v.y, w, false);  // bytes 0,1
    w = __builtin_amdgcn_cvt_pk_fp8_f32(v.z, v.w, w, true);   // bytes 2,3
    return w;
}

// ---------------- prep: fp32->fp8 cast + pos diag dots + local-loss partials ----------------
// one block per pred/gt row (4096 blocks). Each block ALSO streams its 1/4096 slice of
// q_hat/q_real (512 float4 each) — pure HBM streaming at full rate here (R2/R3 lesson:
// loads inside the GEMM's barrier-drained K-loop can't hide). 104 MB of traffic at
// ~6.1 TB/s = at the HBM roofline (R5 measured). Block 0 zero-inits out.
__global__ __launch_bounds__(256) void prep_kernel(
    const float4* __restrict__ pred,
    const float4* __restrict__ gt,
    unsigned int* __restrict__ opred,   // fp8, 256 uints per row
    unsigned int* __restrict__ ogt,
    const float4* __restrict__ qh,
    const float4* __restrict__ qr,
    float* __restrict__ pos,
    float* __restrict__ lpart,          // [4096] per-block local-loss partials
    float* __restrict__ out) {
    __shared__ float sred[4], sred2[4];
    const int row = blockIdx.x;
    const int t = threadIdx.x;
    if (row == 0 && t == 0) out[0] = 0.0f;

    const int idx = row * 256 + t;
    float4 p = pred[idx];
    float4 g = gt[idx];
    opred[idx] = pack_fp8x4(p);
    ogt[idx]   = pack_fp8x4(g);
    float s = p.x * g.x + p.y * g.y + p.z * g.z + p.w * g.w;

    // q slice: 512 float4 per block, 2 per thread
    const int qi = row * 512 + t;
    float4 a0 = qh[qi], b0 = qr[qi];
    float4 a1 = qh[qi + 256], b1 = qr[qi + 256];
    float ls = a0.x * b0.x + a0.y * b0.y + a0.z * b0.z + a0.w * b0.w
             + a1.x * b1.x + a1.y * b1.y + a1.z * b1.z + a1.w * b1.w;

    #pragma unroll
    for (int o = 32; o > 0; o >>= 1) {
        s  += __shfl_down(s, o, 64);
        ls += __shfl_down(ls, o, 64);
    }
    if ((t & 63) == 0) { sred[t >> 6] = s; sred2[t >> 6] = ls; }
    __syncthreads();
    if (t == 0) {
        pos[row]   = sred[0] + sred[1] + sred[2] + sred[3];
        lpart[row] = sred2[0] + sred2[1] + sred2[2] + sred2[3];
    }
}

// ---------------- hinge GEMM (MX fp8, scales=1.0), ping-pong double-buffered ----------------
// sum_ij max(0, <pred_i,gt_j> - pos_i + 1). 128x128 block tile, BK=64 per stage,
// TWO LDS buffers (32 KB total -> 4 blocks/CU), ONE barrier per K-step:
//   barrier(i) drains stage(i); stage(i+1) is issued right after barrier(i) and has the
//   whole compute phase of step i to land before barrier(i+1) drains it. This breaks the
//   zero-distance stage->drain serialization of the 2-barrier m97 structure (R5: 33 us
//   vs ~21 us LDS+MFMA floor).
// LDS layout: 2 tile-rows packed per 128 B LDS row; 16B slot s = unit | ((row&1)<<2)
// stored at phys slot s ^ ((row>>1)&7): staging stays lane-uniform and ds_read_b128
// sits at the 4-access bank-capacity floor.
__global__ __launch_bounds__(256) void hinge_gemm(
    const unsigned char* __restrict__ A,    // pred_fp8 [BROWS][DDIM] row-major, 1024 B/row
    const unsigned char* __restrict__ Bm,   // gt_fp8
    const float* __restrict__ pos,          // [BROWS]
    const float* __restrict__ lpart,        // [4096]
    float* __restrict__ out) {
    __shared__ unsigned char As[2][8192];   // 16 KB (2 buffers x 128 rows x 64 B packed)
    __shared__ unsigned char Bs[2][8192];   // 16 KB
    __shared__ float pos_s[128];
    __shared__ float sred[4];

    const int bm = blockIdx.y;  // row block (pred rows)
    const int bn = blockIdx.x;  // col block (gt rows)
    const int tid = threadIdx.x;
    const int lane = tid & 63;
    const int wave = tid >> 6;
    const int wm = wave >> 1;   // 0..1  wave row within block tile
    const int wn = wave & 1;    // 0..1  wave col

    if (tid < 128) pos_s[tid] = pos[bm * 128 + tid];

    // staging mapping: chunk = 1 KB = 8 LDS rows = 16 tile rows; wave w does chunks
    // {2w, 2w+1} of A and of B. lane l -> LDS dst chunkbase + 16*l (HW-fixed);
    // it FETCHES the global 16B that belongs at its swizzled slot:
    const int j8  = lane >> 3;               // LDS row within chunk (0..7)
    const int sl  = (lane & 7) ^ j8;         // logical slot (3 bits)
    const int str = j8 * 2 + (sl >> 2);      // tile row within 16-row chunk
    const int suo = (sl & 3) * 16;           // byte offset within 64 B k-span

    const unsigned char* Abase = A + (size_t)(bm * 128) * DDIM;
    const unsigned char* Bbase = Bm + (size_t)(bn * 128) * DDIM;

    f32x16 acc[2][2];
    #pragma unroll
    for (int i = 0; i < 2; i++)
        #pragma unroll
        for (int j = 0; j < 2; j++)
            #pragma unroll
            for (int r = 0; r < 16; r++) acc[i][j][r] = 0.0f;

    const int sc1 = 0x7f7f7f7f;        // E8M0 1.0 in every byte
    const int mrow = lane & 31;        // m (or n) within 32x32 tile
    const int kh   = lane >> 5;        // 0..1: which 32-byte k-half of the mfma's K=64

    // fragment read address (lane-constant): tile row r = wbase + mt*32 + mrow
    //   LDS row J = r>>1 = wbase/2 + mt*16 + (mrow>>1);  J&7 = (mrow>>1)&7
    //   slot s = kh*2 | ((mrow&1)<<2); phys = s ^ (J&7); second 16B at addr^16
    const int m_hi = mrow >> 1;
    const int slot = ((kh * 2) | ((mrow & 1) << 2)) ^ (m_hi & 7);
    const int aoff0 = (wm * 32 + m_hi) * 128 + slot * 16;   // + mt*2048
    const int boff0 = (wn * 32 + m_hi) * 128 + slot * 16;   // + nt*2048

    // prologue: stage k-block 0 into buffer 0
    #pragma unroll
    for (int c2 = 0; c2 < 2; c2++) {
        int c = wave * 2 + c2;
        int trow = c * 16 + str;
        __builtin_amdgcn_global_load_lds(
            (gu32*)(Abase + (size_t)trow * DDIM + suo),
            (su32*)(As[0] + c * 1024), 16, 0, 0);
        __builtin_amdgcn_global_load_lds(
            (gu32*)(Bbase + (size_t)trow * DDIM + suo),
            (su32*)(Bs[0] + c * 1024), 16, 0, 0);
    }

    #pragma unroll
    for (int i = 0; i < 16; i++) {          // 16 K-steps of 64
        __syncthreads();                    // drains stage(i) [vmcnt(0)]
        const int cur = i & 1, nxt = cur ^ 1;
        if (i < 15) {
            const int k1 = (i + 1) * 64;
            #pragma unroll
            for (int c2 = 0; c2 < 2; c2++) {
                int c = wave * 2 + c2;
                int trow = c * 16 + str;
                __builtin_amdgcn_global_load_lds(
                    (gu32*)(Abase + (size_t)trow * DDIM + k1 + suo),
                    (su32*)(As[nxt] + c * 1024), 16, 0, 0);
                __builtin_amdgcn_global_load_lds(
                    (gu32*)(Bbase + (size_t)trow * DDIM + k1 + suo),
                    (su32*)(Bs[nxt] + c * 1024), 16, 0, 0);
            }
        }

        i32x8 af[2], bg[2];
        #pragma unroll
        for (int mt = 0; mt < 2; mt++) {
            int o = aoff0 + mt * 2048;
            i32x4 x0 = *(const i32x4*)&As[cur][o];
            i32x4 x1 = *(const i32x4*)&As[cur][o ^ 16];
            af[mt] = __builtin_shufflevector(x0, x1, 0, 1, 2, 3, 4, 5, 6, 7);
        }
        #pragma unroll
        for (int nt = 0; nt < 2; nt++) {
            int o = boff0 + nt * 2048;
            i32x4 x0 = *(const i32x4*)&Bs[cur][o];
            i32x4 x1 = *(const i32x4*)&Bs[cur][o ^ 16];
            bg[nt] = __builtin_shufflevector(x0, x1, 0, 1, 2, 3, 4, 5, 6, 7);
        }
        #pragma unroll
        for (int mt = 0; mt < 2; mt++)
            #pragma unroll
            for (int nt = 0; nt < 2; nt++)
                acc[mt][nt] = __builtin_amdgcn_mfma_scale_f32_32x32x64_f8f6f4(
                    af[mt], bg[nt], acc[mt][nt],
                    0, 0,          // cbsz = A fmt fp8(e4m3), blgp = B fmt fp8
                    0, sc1,        // scale_a opsel, scale_a (1.0)
                    0, sc1);       // scale_b opsel, scale_b (1.0)
    }

    // epilogue: hinge + block reduction + local-loss partial fold
    // 32x32 C/D layout: col = lane&31, row = (reg&3) + 8*(reg>>2) + 4*(lane>>5)
    // [verified m74/m101; dtype-independent m121/m124; R5 passed with absmax 0]
    float s = 0.0f;
    const int rq = 4 * (lane >> 5);
    #pragma unroll
    for (int mt = 0; mt < 2; mt++) {
        #pragma unroll
        for (int nt = 0; nt < 2; nt++) {
            #pragma unroll
            for (int i = 0; i < 16; i++) {
                int lr = wm * 64 + mt * 32 + (i & 3) + 8 * (i >> 2) + rq;
                float v = acc[mt][nt][i] - pos_s[lr] + 1.0f;
                s += fmaxf(v, 0.0f);
            }
        }
    }
    #pragma unroll
    for (int o = 32; o > 0; o >>= 1) s += __shfl_down(s, o, 64);
    if (lane == 0) sred[wave] = s;
    __syncthreads();
    if (tid == 0) {
        const int bid = (bm * 32 + bn) * 4;
        float lp = lpart[bid] + lpart[bid + 1] + lpart[bid + 2] + lpart[bid + 3];
        atomicAdd(out, sred[0] + sred[1] + sred[2] + sred[3]
                       - lp * (1.0f / (float)LROWS));
    }
}

extern "C" void kernel_launch(void* const* d_in, const int* in_sizes, int n_in,
                              void* d_out, int out_size, void* d_ws, size_t ws_size,
                              hipStream_t stream) {
    const float* q_hat  = (const float*)d_in[0];
    const float* q_real = (const float*)d_in[1];
    const float* gt     = (const float*)d_in[2];  // encoded_gt
    const float* pred   = (const float*)d_in[3];  // encoded_pred
    float* out = (float*)d_out;

    // workspace layout: pred_fp8 (4MB) | gt_fp8 (4MB) | pos (16KB) | lpart (16KB)
    char* ws = (char*)d_ws;
    unsigned char* pred_8 = (unsigned char*)ws;
    unsigned char* gt_8   = (unsigned char*)(ws + (size_t)BROWS * DDIM);
    float* pos   = (float*)(ws + (size_t)2 * BROWS * DDIM);
    float* lpart = (float*)(ws + (size_t)2 * BROWS * DDIM + BROWS * 4);

    hipLaunchKernelGGL(prep_kernel, dim3(BROWS), dim3(256), 0, stream,
                       (const float4*)pred, (const float4*)gt,
                       (unsigned int*)pred_8, (unsigned int*)gt_8,
                       (const float4*)q_hat, (const float4*)q_real,
                       pos, lpart, out);

    hipLaunchKernelGGL(hinge_gemm, dim3(32, 32), dim3(256), 0, stream,
                       pred_8, gt_8, pos, lpart, out);
}

// Round 7
// 146.393 us; speedup vs baseline: 1.0090x; 1.0090x over previous
//
#include <hip/hip_runtime.h>
#include <hip/hip_bf16.h>

// Problem sizes (fixed by the reference)
#define LROWS 8192
#define BROWS 4096
#define DDIM  1024

typedef __attribute__((ext_vector_type(4)))  int   i32x4;
typedef __attribute__((ext_vector_type(8)))  int   i32x8;
typedef __attribute__((ext_vector_type(16))) float f32x16;

// address-space-qualified pointer typedefs for global_load_lds
typedef const unsigned int __attribute__((address_space(1))) gu32;
typedef unsigned int       __attribute__((address_space(3))) su32;

// pack 4 floats -> 4 fp8 e4m3 bytes (OCP e4m3fn on gfx950)
__device__ inline unsigned int pack_fp8x4(float4 v) {
    unsigned int w = 0;
    w = __builtin_amdgcn_cvt_pk_fp8_f32(v.x, v.y, w, false);  // bytes 0,1
    w = __builtin_amdgcn_cvt_pk_fp8_f32(v.z, v.w, w, true);   // bytes 2,3
    return w;
}

// ---------------- prep: fp32->fp8 cast + pos diag dots + local-loss partials ----------------
// one block per pred/gt row (4096 blocks). Each block ALSO streams its 1/4096 slice of
// q_hat/q_real (512 float4 each) — pure HBM streaming at full rate here (R2/R3 lesson:
// loads inside the GEMM's barrier-drained K-loop can't hide). 104 MB of mandatory
// traffic at ~6.1 TB/s = HBM roofline (R5 measured). Block 0 zero-inits out.
__global__ __launch_bounds__(256) void prep_kernel(
    const float4* __restrict__ pred,
    const float4* __restrict__ gt,
    unsigned int* __restrict__ opred,   // fp8, 256 uints per row
    unsigned int* __restrict__ ogt,
    const float4* __restrict__ qh,
    const float4* __restrict__ qr,
    float* __restrict__ pos,
    float* __restrict__ lpart,          // [4096] per-block local-loss partials
    float* __restrict__ out) {
    __shared__ float sred[4], sred2[4];
    const int row = blockIdx.x;
    const int t = threadIdx.x;
    if (row == 0 && t == 0) out[0] = 0.0f;

    const int idx = row * 256 + t;
    float4 p = pred[idx];
    float4 g = gt[idx];
    opred[idx] = pack_fp8x4(p);
    ogt[idx]   = pack_fp8x4(g);
    float s = p.x * g.x + p.y * g.y + p.z * g.z + p.w * g.w;

    // q slice: 512 float4 per block, 2 per thread
    const int qi = row * 512 + t;
    float4 a0 = qh[qi], b0 = qr[qi];
    float4 a1 = qh[qi + 256], b1 = qr[qi + 256];
    float ls = a0.x * b0.x + a0.y * b0.y + a0.z * b0.z + a0.w * b0.w
             + a1.x * b1.x + a1.y * b1.y + a1.z * b1.z + a1.w * b1.w;

    #pragma unroll
    for (int o = 32; o > 0; o >>= 1) {
        s  += __shfl_down(s, o, 64);
        ls += __shfl_down(ls, o, 64);
    }
    if ((t & 63) == 0) { sred[t >> 6] = s; sred2[t >> 6] = ls; }
    __syncthreads();
    if (t == 0) {
        pos[row]   = sred[0] + sred[1] + sred[2] + sred[3];
        lpart[row] = sred2[0] + sred2[1] + sred2[2] + sred2[3];
    }
}

// ---------------- hinge GEMM (MX fp8, scales=1.0): sum_ij max(0,<p_i,g_j>-pos_i+1) ----------------
// Best measured configuration (R5: hinge ~33 us, ~1040 TF). 128x128 block tile, BK=128
// staged (32 KB LDS, 4 blocks/CU), 4 waves, each wave 64x64 = 2x2 of
// mfma_scale_f32_32x32x64_f8f6f4 (fp8/fp8, E8M0 scale 0x7F = 1.0) -> 2x non-scaled fp8 rate.
// LDS rows are 128 B; 16B units XOR-swizzled by (row&7): staging stays lane-uniform
// ((lane&7)^(lane>>3)) and fragment ds_read_b128s sit at the bank-capacity floor.
// NOTE R6 post-mortem: ping-pong dbuf (BK=64, 1 barrier/step) measured NEUTRAL — the
// barrier vmcnt(0) drain is structural (m99/m100/m131-m141 reproduced); cross-block
// overlap at 4 blocks/CU is the hiding mechanism and it saturates here.
__global__ __launch_bounds__(256) void hinge_gemm(
    const unsigned char* __restrict__ A,    // pred_fp8 [BROWS][DDIM] row-major, 1024 B/row
    const unsigned char* __restrict__ Bm,   // gt_fp8
    const float* __restrict__ pos,          // [BROWS]
    const float* __restrict__ lpart,        // [4096]
    float* __restrict__ out) {
    __shared__ unsigned char As[128 * 128];  // 16 KB
    __shared__ unsigned char Bs[128 * 128];  // 16 KB
    __shared__ float pos_s[128];
    __shared__ float sred[4];

    const int bm = blockIdx.y;  // row block (pred rows)
    const int bn = blockIdx.x;  // col block (gt rows)
    const int tid = threadIdx.x;
    const int lane = tid & 63;
    const int wave = tid >> 6;
    const int wm = wave >> 1;   // 0..1  wave row within block tile
    const int wn = wave & 1;    // 0..1  wave col

    if (tid < 128) pos_s[tid] = pos[bm * 128 + tid];

    // staging: 16 chunks of 1 KB per matrix (128 rows x 128 B). wave w stages chunks
    // w*4..w*4+3 of A and of B; each chunk = 8 rows. lane l -> row_in_chunk l>>3,
    // phys 16B unit l&3; it fetches LOGICAL unit (l&7)^(l>>3) so the tile lands
    // swizzled: phys_unit = log_unit ^ (row&7).
    const int grow = lane >> 3;                 // 0..7
    const int usw  = (lane & 7) ^ grow;         // logical unit this lane fetches

    const unsigned char* Abase = A + (size_t)(bm * 128) * DDIM;
    const unsigned char* Bbase = Bm + (size_t)(bn * 128) * DDIM;

    f32x16 acc[2][2];
    #pragma unroll
    for (int i = 0; i < 2; i++)
        #pragma unroll
        for (int j = 0; j < 2; j++)
            #pragma unroll
            for (int r = 0; r < 16; r++) acc[i][j][r] = 0.0f;

    const int sc1 = 0x7f7f7f7f;        // E8M0 1.0 in every byte
    const int mrow = lane & 31;        // m (or n) within 32x32 tile
    const int kh = lane >> 5;          // 0..1: which 32-byte k-half of the mfma's K=64

    for (int k0 = 0; k0 < DDIM; k0 += 128) {
        #pragma unroll
        for (int i = 0; i < 4; i++) {
            int c = wave * 4 + i;           // chunk 0..15
            int row = c * 8 + grow;         // tile row 0..127
            __builtin_amdgcn_global_load_lds(
                (gu32*)(Abase + (size_t)row * DDIM + k0 + usw * 16),
                (su32*)(As + c * 1024), 16, 0, 0);
            __builtin_amdgcn_global_load_lds(
                (gu32*)(Bbase + (size_t)row * DDIM + k0 + usw * 16),
                (su32*)(Bs + c * 1024), 16, 0, 0);
        }
        __syncthreads();

        #pragma unroll
        for (int h = 0; h < 2; h++) {      // two K=64 mfma steps per staged BK=128
            const int u0 = h * 4 + kh * 2; // logical 16B unit of this lane's k-block
            i32x8 af[2], bg[2];
            #pragma unroll
            for (int mt = 0; mt < 2; mt++) {
                int r = wm * 64 + mt * 32 + mrow;
                i32x4 x0 = *(const i32x4*)&As[r * 128 + ((u0    ) ^ (r & 7)) * 16];
                i32x4 x1 = *(const i32x4*)&As[r * 128 + ((u0 + 1) ^ (r & 7)) * 16];
                af[mt] = __builtin_shufflevector(x0, x1, 0, 1, 2, 3, 4, 5, 6, 7);
            }
            #pragma unroll
            for (int nt = 0; nt < 2; nt++) {
                int r = wn * 64 + nt * 32 + mrow;
                i32x4 x0 = *(const i32x4*)&Bs[r * 128 + ((u0    ) ^ (r & 7)) * 16];
                i32x4 x1 = *(const i32x4*)&Bs[r * 128 + ((u0 + 1) ^ (r & 7)) * 16];
                bg[nt] = __builtin_shufflevector(x0, x1, 0, 1, 2, 3, 4, 5, 6, 7);
            }
            #pragma unroll
            for (int mt = 0; mt < 2; mt++)
                #pragma unroll
                for (int nt = 0; nt < 2; nt++)
                    acc[mt][nt] = __builtin_amdgcn_mfma_scale_f32_32x32x64_f8f6f4(
                        af[mt], bg[nt], acc[mt][nt],
                        0, 0,          // cbsz = A fmt fp8(e4m3), blgp = B fmt fp8
                        0, sc1,        // scale_a opsel, scale_a (1.0)
                        0, sc1);       // scale_b opsel, scale_b (1.0)
        }
        __syncthreads();
    }

    // epilogue: hinge + block reduction + local-loss partial fold
    // 32x32 C/D layout: col = lane&31, row = (reg&3) + 8*(reg>>2) + 4*(lane>>5)
    // [verified m74/m101; dtype-independent m121/m124; R5 passed with absmax 0]
    float s = 0.0f;
    const int rq = 4 * (lane >> 5);
    #pragma unroll
    for (int mt = 0; mt < 2; mt++) {
        #pragma unroll
        for (int nt = 0; nt < 2; nt++) {
            #pragma unroll
            for (int i = 0; i < 16; i++) {
                int lr = wm * 64 + mt * 32 + (i & 3) + 8 * (i >> 2) + rq;
                float v = acc[mt][nt][i] - pos_s[lr] + 1.0f;
                s += fmaxf(v, 0.0f);
            }
        }
    }
    #pragma unroll
    for (int o = 32; o > 0; o >>= 1) s += __shfl_down(s, o, 64);
    if (lane == 0) sred[wave] = s;
    __syncthreads();
    if (tid == 0) {
        const int bid = (bm * 32 + bn) * 4;
        float lp = lpart[bid] + lpart[bid + 1] + lpart[bid + 2] + lpart[bid + 3];
        atomicAdd(out, sred[0] + sred[1] + sred[2] + sred[3]
                       - lp * (1.0f / (float)LROWS));
    }
}

extern "C" void kernel_launch(void* const* d_in, const int* in_sizes, int n_in,
                              void* d_out, int out_size, void* d_ws, size_t ws_size,
                              hipStream_t stream) {
    const float* q_hat  = (const float*)d_in[0];
    const float* q_real = (const float*)d_in[1];
    const float* gt     = (const float*)d_in[2];  // encoded_gt
    const float* pred   = (const float*)d_in[3];  // encoded_pred
    float* out = (float*)d_out;

    // workspace layout: pred_fp8 (4MB) | gt_fp8 (4MB) | pos (16KB) | lpart (16KB)
    char* ws = (char*)d_ws;
    unsigned char* pred_8 = (unsigned char*)ws;
    unsigned char* gt_8   = (unsigned char*)(ws + (size_t)BROWS * DDIM);
    float* pos   = (float*)(ws + (size_t)2 * BROWS * DDIM);
    float* lpart = (float*)(ws + (size_t)2 * BROWS * DDIM + BROWS * 4);

    hipLaunchKernelGGL(prep_kernel, dim3(BROWS), dim3(256), 0, stream,
                       (const float4*)pred, (const float4*)gt,
                       (unsigned int*)pred_8, (unsigned int*)gt_8,
                       (const float4*)q_hat, (const float4*)q_real,
                       pos, lpart, out);

    hipLaunchKernelGGL(hinge_gemm, dim3(32, 32), dim3(256), 0, stream,
                       pred_8, gt_8, pos, lpart, out);
}